// Round 10
// baseline (518.872 us; speedup 1.0000x reference)
//
#include <hip/hip_runtime.h>

#define VSZ 32000
#define ESZ 150
#define HSZ 30
#define SSZ 128
#define BSZ 32
#define SB  4096   /* SSZ*BSZ */
#define KP  64     /* padded K: 60 dims + bias row + 3 zeros */

typedef __attribute__((ext_vector_type(8))) short bf16x8;
typedef __attribute__((ext_vector_type(4))) float f32x4;
typedef __attribute__((ext_vector_type(8))) unsigned short u16x8;

static __device__ __forceinline__ unsigned short f2bf(float f) {
  unsigned int u = __float_as_uint(f);
  u += 0x7fffu + ((u >> 16) & 1u);   // round-to-nearest-even
  return (unsigned short)(u >> 16);
}

static __device__ __forceinline__ float readlane_f(float v, int lane) {
  return __uint_as_float(__builtin_amdgcn_readlane(__float_as_uint(v), lane));
}

// ---------------------------------------------------------------------------
// K1: input projection  z[dir][t][b][j] = b_ih[j] + sum_e emb[idx[t,b]][e]*W[e][j]
// ---------------------------------------------------------------------------
__global__ void k_zproj(const int* __restrict__ idx, const float* __restrict__ emb,
                        const float* __restrict__ Wlr, const float* __restrict__ blr,
                        const float* __restrict__ Wrl, const float* __restrict__ brl,
                        float* __restrict__ z) {
  __shared__ float erow[ESZ];
  int tb = blockIdx.x;                 // t*32 + b
  int row = idx[tb];
  for (int i = threadIdx.x; i < ESZ; i += 64) erow[i] = emb[row * ESZ + i];
  __syncthreads();
  int lane = threadIdx.x;
  int j = lane & 31, dir = lane >> 5;
  if (j < HSZ) {
    const float* W = dir ? Wrl : Wlr;
    float acc = dir ? brl[j] : blr[j];
#pragma unroll 10
    for (int e = 0; e < ESZ; ++e) acc = fmaf(erow[e], W[e * HSZ + j], acc);
    z[(dir * SB + tb) * HSZ + j] = acc;   // z[dir][t][b][j]
  }
}

// ---------------------------------------------------------------------------
// K2: recurrent scans. 64 blocks x 64 threads; 1 chain (dir,b) per wave.
// ---------------------------------------------------------------------------
__global__ void k_scan(const float* __restrict__ z, const float* __restrict__ Wlr,
                       const float* __restrict__ Wrl, const float* __restrict__ h0,
                       unsigned short* __restrict__ hcat) {
  int j = threadIdx.x;                     // 0..63
  int chain = blockIdx.x;                  // 0..63
  int dir = chain >> 5, b = chain & 31;
  const float* W = dir ? Wrl : Wlr;
  float w2[HSZ];
#pragma unroll
  for (int k = 0; k < HSZ; ++k) w2[k] = (j < HSZ) ? W[(ESZ + k) * HSZ + j] : 0.f;
  float h = (j < HSZ) ? h0[j] : 0.f;
  bool wr = (j < 32);
  int dim = (j < HSZ) ? dir * HSZ + j : (dir ? 60 : 62) + (j - 30);
  unsigned short padbits = (dim == 60) ? f2bf(1.0f) : (unsigned short)0;
  const float* zc = z + dir * (SB * HSZ) + b * HSZ + j;
  int te0 = dir ? (SSZ - 1) : 0;
  float zv = (j < HSZ) ? zc[te0 * (BSZ * HSZ)] : 0.f;
  for (int t = 0; t < SSZ; ++t) {
    int te = dir ? (SSZ - 1 - t) : t;
    float zn = 0.f;
    if (t < SSZ - 1) {
      int ten = dir ? (SSZ - 2 - t) : (t + 1);
      zn = (j < HSZ) ? zc[ten * (BSZ * HSZ)] : 0.f;
    }
    int r = te * BSZ + b;
    if (wr) hcat[r * KP + dim] = (j < HSZ) ? f2bf(h) : padbits;  // pre-update state
    float a0 = zv, a1 = 0.f, a2 = 0.f, a3 = 0.f;
#pragma unroll
    for (int k = 0; k < 28; k += 4) {
      a0 = fmaf(readlane_f(h, k),     w2[k],     a0);
      a1 = fmaf(readlane_f(h, k + 1), w2[k + 1], a1);
      a2 = fmaf(readlane_f(h, k + 2), w2[k + 2], a2);
      a3 = fmaf(readlane_f(h, k + 3), w2[k + 3], a3);
    }
    a0 = fmaf(readlane_f(h, 28), w2[28], a0);
    a1 = fmaf(readlane_f(h, 29), w2[29], a1);
    float x = (a0 + a1) + (a2 + a3);
    float e = __expf(2.0f * x);
    h = 1.0f - __fdividef(2.0f, e + 1.0f);
    zv = zn;
  }
}

// ---------------------------------------------------------------------------
// K3: Wbt[v][k] (bf16, transposed W_ho, k=60 -> b_ho, 61..63 -> 0)
// ---------------------------------------------------------------------------
__global__ void k_wprep(const float* __restrict__ Who, const float* __restrict__ bho,
                        unsigned short* __restrict__ Wbt) {
  int v = blockIdx.x * 256 + threadIdx.x;
  int kq = blockIdx.y;
  u16x8 pack;
#pragma unroll
  for (int i = 0; i < 8; ++i) {
    int k = kq * 8 + i;
    float val = (k < 60) ? Who[k * VSZ + v] : ((k == 60) ? bho[v] : 0.f);
    pack[i] = f2bf(val);
  }
  *(u16x8*)&Wbt[v * KP + kq * 8] = pack;
}

// ---------------------------------------------------------------------------
// K4: pass A — per-row sum of exp(logit). Swapped-operand MFMA. (unchanged R2)
// grid (32 Mblk, 16 Nblk) x 256. Block: 128 rows x 2000 cols; wave: 32 rows.
// ---------------------------------------------------------------------------
__global__ void k_sumexp(const unsigned short* __restrict__ hcat,
                         const unsigned short* __restrict__ Wbt,
                         float* __restrict__ part) {
  int mb = blockIdx.x, nb = blockIdx.y;
  int wave = threadIdx.x >> 6, lane = threadIdx.x & 63;
  int g = lane >> 4, c = lane & 15;
  int rbase = mb * 128 + wave * 32;
  bf16x8 bfr[2][2];                       // [row-group][k-split], held in regs
#pragma unroll
  for (int rg = 0; rg < 2; ++rg)
#pragma unroll
    for (int ks = 0; ks < 2; ++ks)
      bfr[rg][ks] = *(const bf16x8*)&hcat[(rbase + rg * 16 + c) * KP + ks * 32 + g * 8];
  float se[2] = {0.f, 0.f};
  int c0 = nb * 2000;
  for (int nt = 0; nt < 125; ++nt) {
    int ct = c0 + nt * 16;
    bf16x8 a0 = *(const bf16x8*)&Wbt[(ct + c) * KP + g * 8];
    bf16x8 a1 = *(const bf16x8*)&Wbt[(ct + c) * KP + 32 + g * 8];
#pragma unroll
    for (int rg = 0; rg < 2; ++rg) {
      f32x4 acc = {0.f, 0.f, 0.f, 0.f};
      acc = __builtin_amdgcn_mfma_f32_16x16x32_bf16(a0, bfr[rg][0], acc, 0, 0, 0);
      acc = __builtin_amdgcn_mfma_f32_16x16x32_bf16(a1, bfr[rg][1], acc, 0, 0, 0);
      se[rg] += (__expf(acc[0]) + __expf(acc[1])) + (__expf(acc[2]) + __expf(acc[3]));
    }
  }
#pragma unroll
  for (int rg = 0; rg < 2; ++rg) {
    se[rg] += __shfl_xor(se[rg], 16);
    se[rg] += __shfl_xor(se[rg], 32);
  }
  if (g == 0) {
#pragma unroll
    for (int rg = 0; rg < 2; ++rg)
      part[(rbase + rg * 16 + c) * 16 + nb] = se[rg];
  }
}

// ---------------------------------------------------------------------------
// K5: pass B — EXACT R5 structure, body runs THREE times per dispatch
// (idempotent). ~440us dispatch => #1 in rocprof top-5 => counters finally
// visible for the writeout body. Pure counter probe: rep-deltas also split
// cold-pass vs steady-state cost (R7 gave rep1=202, rep2=121).
// grid (64, 16) x 256.
// ---------------------------------------------------------------------------
__global__ __launch_bounds__(256) void k_writeout(
    const unsigned short* __restrict__ hcat,
    const unsigned short* __restrict__ Wbt,
    const float* __restrict__ part,
    float* __restrict__ out) {
  __shared__ float Lsh[64];
  __shared__ float slab[4][16 * 64];     // 4 waves x 4 KB
  int mb = blockIdx.x, nb = blockIdx.y;
  int tid = threadIdx.x;
  if (tid < 64) {
    const float* p = &part[(mb * 64 + tid) * 16];
    float s = 0.f;
#pragma unroll
    for (int k = 0; k < 16; ++k) s += p[k];
    Lsh[tid] = logf(s);
  }
  __syncthreads();
  int wave = tid >> 6, lane = tid & 63;
  int g = lane >> 4, c = lane & 15;
  int row0 = mb * 64 + wave * 16;
  bf16x8 b0f = *(const bf16x8*)&hcat[(row0 + c) * KP + g * 8];
  bf16x8 b1f = *(const bf16x8*)&hcat[(row0 + c) * KP + 32 + g * 8];
  float L = Lsh[wave * 16 + c];
  float* tl = slab[wave];
  int c0 = nb * 2000;
  for (int rep = 0; rep < 3; ++rep) {
    for (int gq = 0; gq < 31; ++gq) {    // 31 groups of 4 tiles = cols 0..1983
      int ct0 = c0 + gq * 64;
#pragma unroll
      for (int t = 0; t < 4; ++t) {
        int ct = ct0 + t * 16;
        bf16x8 a0 = *(const bf16x8*)&Wbt[(ct + c) * KP + g * 8];
        bf16x8 a1 = *(const bf16x8*)&Wbt[(ct + c) * KP + 32 + g * 8];
        f32x4 acc = {0.f, 0.f, 0.f, 0.f};
        acc = __builtin_amdgcn_mfma_f32_16x16x32_bf16(a0, b0f, acc, 0, 0, 0);
        acc = __builtin_amdgcn_mfma_f32_16x16x32_bf16(a1, b1f, acc, 0, 0, 0);
        f32x4 v;
#pragma unroll
        for (int i = 0; i < 4; ++i) v[i] = acc[i] - L;
        int P = (t * 4 + g) ^ (c & 7);   // granule swizzle: row c, granule t*4+g
        *(f32x4*)&tl[c * 64 + P * 4] = v;
      }
#pragma unroll
      for (int j = 0; j < 4; ++j) {      // flush: rows 4j+g, 256 B runs
        int rj = 4 * j + g;
        int P = c ^ (rj & 7);
        f32x4 w = *(f32x4*)&tl[rj * 64 + P * 4];
        __builtin_nontemporal_store(w, (f32x4*)&out[(row0 + rj) * VSZ + ct0 + c * 4]);
      }
    }
    {                                    // tail tile: cols 1984..1999, direct
      int ct = c0 + 1984;
      bf16x8 a0 = *(const bf16x8*)&Wbt[(ct + c) * KP + g * 8];
      bf16x8 a1 = *(const bf16x8*)&Wbt[(ct + c) * KP + 32 + g * 8];
      f32x4 acc = {0.f, 0.f, 0.f, 0.f};
      acc = __builtin_amdgcn_mfma_f32_16x16x32_bf16(a0, b0f, acc, 0, 0, 0);
      acc = __builtin_amdgcn_mfma_f32_16x16x32_bf16(a1, b1f, acc, 0, 0, 0);
      f32x4 v;
#pragma unroll
      for (int i = 0; i < 4; ++i) v[i] = acc[i] - L;
      *(f32x4*)&out[(row0 + c) * VSZ + ct + g * 4] = v;
    }
    asm volatile("" ::: "memory");       // keep all reps' stores alive
  }
}

// ---------------------------------------------------------------------------
extern "C" void kernel_launch(void* const* d_in, const int* in_sizes, int n_in,
                              void* d_out, int out_size, void* d_ws, size_t ws_size,
                              hipStream_t stream) {
  (void)in_sizes; (void)n_in; (void)out_size; (void)ws_size;
  const int*   idx = (const int*)d_in[0];
  const float* emb = (const float*)d_in[1];
  const float* Wlr = (const float*)d_in[2];
  const float* blr = (const float*)d_in[3];
  const float* Wrl = (const float*)d_in[4];
  const float* brl = (const float*)d_in[5];
  const float* Who = (const float*)d_in[6];
  const float* bho = (const float*)d_in[7];
  const float* h0  = (const float*)d_in[8];
  float* out = (float*)d_out;

  char* ws = (char*)d_ws;
  float*          z    = (float*)(ws + 0);                 // 983040 B
  unsigned short* hcat = (unsigned short*)(ws + 983040);   // 524288 B
  unsigned short* Wbt  = (unsigned short*)(ws + 1507328);  // 4096000 B
  float*          part = (float*)(ws + 5603328);           // 262144 B

  k_zproj<<<SB, 64, 0, stream>>>(idx, emb, Wlr, blr, Wrl, brl, z);
  k_scan<<<64, 64, 0, stream>>>(z, Wlr, Wrl, h0, hcat);
  k_wprep<<<dim3(125, 8), 256, 0, stream>>>(Who, bho, Wbt);
  k_sumexp<<<dim3(32, 16), 256, 0, stream>>>(hcat, Wbt, part);
  k_writeout<<<dim3(64, 16), 256, 0, stream>>>(hcat, Wbt, part, out);
}

// Round 11
// 347.586 us; speedup vs baseline: 1.4928x; 1.4928x over previous
//
#include <hip/hip_runtime.h>

#define VSZ 32000
#define ESZ 150
#define HSZ 30
#define SSZ 128
#define BSZ 32
#define SB  4096   /* SSZ*BSZ */
#define KP  64     /* padded K: 60 dims + bias row + 3 zeros */

typedef __attribute__((ext_vector_type(8))) short bf16x8;
typedef __attribute__((ext_vector_type(4))) float f32x4;
typedef __attribute__((ext_vector_type(8))) unsigned short u16x8;

static __device__ __forceinline__ unsigned short f2bf(float f) {
  unsigned int u = __float_as_uint(f);
  u += 0x7fffu + ((u >> 16) & 1u);   // round-to-nearest-even
  return (unsigned short)(u >> 16);
}

static __device__ __forceinline__ float readlane_f(float v, int lane) {
  return __uint_as_float(__builtin_amdgcn_readlane(__float_as_uint(v), lane));
}

// ---------------------------------------------------------------------------
// K1: merged prep — blocks 0..1023: input projection (4 tb per block, one per
// wave); blocks 1024..2023: Wbt transpose/pack. The two halves are fully
// independent; merging saves one dispatch boundary.
// ---------------------------------------------------------------------------
__global__ __launch_bounds__(256) void k_prep(
    const int* __restrict__ idx, const float* __restrict__ emb,
    const float* __restrict__ Wlr, const float* __restrict__ blr,
    const float* __restrict__ Wrl, const float* __restrict__ brl,
    float* __restrict__ z,
    const float* __restrict__ Who, const float* __restrict__ bho,
    unsigned short* __restrict__ Wbt) {
  int bid = blockIdx.x;
  if (bid < 1024) {
    // ---- zproj: z[dir][t][b][j] = b_ih[j] + sum_e emb[idx[t,b]][e]*W[e][j]
    __shared__ float erow[4][ESZ];
    int wave = threadIdx.x >> 6, lane = threadIdx.x & 63;
    int tb = bid * 4 + wave;             // t*32 + b
    int row = idx[tb];
    for (int i = lane; i < ESZ; i += 64) erow[wave][i] = emb[row * ESZ + i];
    __syncthreads();
    int j = lane & 31, dir = lane >> 5;
    if (j < HSZ) {
      const float* W = dir ? Wrl : Wlr;
      float acc = dir ? brl[j] : blr[j];
#pragma unroll 10
      for (int e = 0; e < ESZ; ++e) acc = fmaf(erow[wave][e], W[e * HSZ + j], acc);
      z[(dir * SB + tb) * HSZ + j] = acc;   // z[dir][t][b][j]
    }
  } else {
    // ---- wprep: Wbt[v][k] (bf16, transposed W_ho; k=60 -> b_ho, 61..63 -> 0)
    int b2 = bid - 1024;                 // 0..999
    int v = (b2 % 125) * 256 + threadIdx.x;
    int kq = b2 / 125;
    u16x8 pack;
#pragma unroll
    for (int i = 0; i < 8; ++i) {
      int k = kq * 8 + i;
      float val = (k < 60) ? Who[k * VSZ + v] : ((k == 60) ? bho[v] : 0.f);
      pack[i] = f2bf(val);
    }
    *(u16x8*)&Wbt[v * KP + kq * 8] = pack;
  }
}

// ---------------------------------------------------------------------------
// K2: recurrent scans. 64 blocks x 64 threads; 1 chain (dir,b) per wave.
// ---------------------------------------------------------------------------
__global__ void k_scan(const float* __restrict__ z, const float* __restrict__ Wlr,
                       const float* __restrict__ Wrl, const float* __restrict__ h0,
                       unsigned short* __restrict__ hcat) {
  int j = threadIdx.x;                     // 0..63
  int chain = blockIdx.x;                  // 0..63
  int dir = chain >> 5, b = chain & 31;
  const float* W = dir ? Wrl : Wlr;
  float w2[HSZ];
#pragma unroll
  for (int k = 0; k < HSZ; ++k) w2[k] = (j < HSZ) ? W[(ESZ + k) * HSZ + j] : 0.f;
  float h = (j < HSZ) ? h0[j] : 0.f;
  bool wr = (j < 32);
  int dim = (j < HSZ) ? dir * HSZ + j : (dir ? 60 : 62) + (j - 30);
  unsigned short padbits = (dim == 60) ? f2bf(1.0f) : (unsigned short)0;
  const float* zc = z + dir * (SB * HSZ) + b * HSZ + j;
  int te0 = dir ? (SSZ - 1) : 0;
  float zv = (j < HSZ) ? zc[te0 * (BSZ * HSZ)] : 0.f;
  for (int t = 0; t < SSZ; ++t) {
    int te = dir ? (SSZ - 1 - t) : t;
    float zn = 0.f;
    if (t < SSZ - 1) {
      int ten = dir ? (SSZ - 2 - t) : (t + 1);
      zn = (j < HSZ) ? zc[ten * (BSZ * HSZ)] : 0.f;
    }
    int r = te * BSZ + b;
    if (wr) hcat[r * KP + dim] = (j < HSZ) ? f2bf(h) : padbits;  // pre-update state
    float a0 = zv, a1 = 0.f, a2 = 0.f, a3 = 0.f;
#pragma unroll
    for (int k = 0; k < 28; k += 4) {
      a0 = fmaf(readlane_f(h, k),     w2[k],     a0);
      a1 = fmaf(readlane_f(h, k + 1), w2[k + 1], a1);
      a2 = fmaf(readlane_f(h, k + 2), w2[k + 2], a2);
      a3 = fmaf(readlane_f(h, k + 3), w2[k + 3], a3);
    }
    a0 = fmaf(readlane_f(h, 28), w2[28], a0);
    a1 = fmaf(readlane_f(h, 29), w2[29], a1);
    float x = (a0 + a1) + (a2 + a3);
    float e = __expf(2.0f * x);
    h = 1.0f - __fdividef(2.0f, e + 1.0f);
    zv = zn;
  }
}

// ---------------------------------------------------------------------------
// K3: pass A — per-row sum of exp(logit). Swapped-operand MFMA. (unchanged R2)
// grid (32 Mblk, 16 Nblk) x 256. Block: 128 rows x 2000 cols; wave: 32 rows.
// ---------------------------------------------------------------------------
__global__ void k_sumexp(const unsigned short* __restrict__ hcat,
                         const unsigned short* __restrict__ Wbt,
                         float* __restrict__ part) {
  int mb = blockIdx.x, nb = blockIdx.y;
  int wave = threadIdx.x >> 6, lane = threadIdx.x & 63;
  int g = lane >> 4, c = lane & 15;
  int rbase = mb * 128 + wave * 32;
  bf16x8 bfr[2][2];                       // [row-group][k-split], held in regs
#pragma unroll
  for (int rg = 0; rg < 2; ++rg)
#pragma unroll
    for (int ks = 0; ks < 2; ++ks)
      bfr[rg][ks] = *(const bf16x8*)&hcat[(rbase + rg * 16 + c) * KP + ks * 32 + g * 8];
  float se[2] = {0.f, 0.f};
  int c0 = nb * 2000;
  for (int nt = 0; nt < 125; ++nt) {
    int ct = c0 + nt * 16;
    bf16x8 a0 = *(const bf16x8*)&Wbt[(ct + c) * KP + g * 8];
    bf16x8 a1 = *(const bf16x8*)&Wbt[(ct + c) * KP + 32 + g * 8];
#pragma unroll
    for (int rg = 0; rg < 2; ++rg) {
      f32x4 acc = {0.f, 0.f, 0.f, 0.f};
      acc = __builtin_amdgcn_mfma_f32_16x16x32_bf16(a0, bfr[rg][0], acc, 0, 0, 0);
      acc = __builtin_amdgcn_mfma_f32_16x16x32_bf16(a1, bfr[rg][1], acc, 0, 0, 0);
      se[rg] += (__expf(acc[0]) + __expf(acc[1])) + (__expf(acc[2]) + __expf(acc[3]));
    }
  }
#pragma unroll
  for (int rg = 0; rg < 2; ++rg) {
    se[rg] += __shfl_xor(se[rg], 16);
    se[rg] += __shfl_xor(se[rg], 32);
  }
  if (g == 0) {
#pragma unroll
    for (int rg = 0; rg < 2; ++rg)
      part[(rbase + rg * 16 + c) * 16 + nb] = se[rg];
  }
}

// ---------------------------------------------------------------------------
// K4: pass B — EXACT R5 structure except the flush stores are PLAIN (no
// nontemporal hint): R10 counters showed clean traffic (no amplification) at
// only 4 TB/s, while the harness fill hits 6.8 TB/s with plain stores on the
// same buffer — testing whether NT was defeating LLC write absorption.
// grid (64, 16) x 256.
// ---------------------------------------------------------------------------
__global__ __launch_bounds__(256) void k_writeout(
    const unsigned short* __restrict__ hcat,
    const unsigned short* __restrict__ Wbt,
    const float* __restrict__ part,
    float* __restrict__ out) {
  __shared__ float Lsh[64];
  __shared__ float slab[4][16 * 64];     // 4 waves x 4 KB
  int mb = blockIdx.x, nb = blockIdx.y;
  int tid = threadIdx.x;
  if (tid < 64) {
    const float* p = &part[(mb * 64 + tid) * 16];
    float s = 0.f;
#pragma unroll
    for (int k = 0; k < 16; ++k) s += p[k];
    Lsh[tid] = logf(s);
  }
  __syncthreads();
  int wave = tid >> 6, lane = tid & 63;
  int g = lane >> 4, c = lane & 15;
  int row0 = mb * 64 + wave * 16;
  bf16x8 b0f = *(const bf16x8*)&hcat[(row0 + c) * KP + g * 8];
  bf16x8 b1f = *(const bf16x8*)&hcat[(row0 + c) * KP + 32 + g * 8];
  float L = Lsh[wave * 16 + c];
  float* tl = slab[wave];
  int c0 = nb * 2000;
  for (int gq = 0; gq < 31; ++gq) {      // 31 groups of 4 tiles = cols 0..1983
    int ct0 = c0 + gq * 64;
#pragma unroll
    for (int t = 0; t < 4; ++t) {
      int ct = ct0 + t * 16;
      bf16x8 a0 = *(const bf16x8*)&Wbt[(ct + c) * KP + g * 8];
      bf16x8 a1 = *(const bf16x8*)&Wbt[(ct + c) * KP + 32 + g * 8];
      f32x4 acc = {0.f, 0.f, 0.f, 0.f};
      acc = __builtin_amdgcn_mfma_f32_16x16x32_bf16(a0, b0f, acc, 0, 0, 0);
      acc = __builtin_amdgcn_mfma_f32_16x16x32_bf16(a1, b1f, acc, 0, 0, 0);
      f32x4 v;
#pragma unroll
      for (int i = 0; i < 4; ++i) v[i] = acc[i] - L;
      int P = (t * 4 + g) ^ (c & 7);     // granule swizzle: row c, granule t*4+g
      *(f32x4*)&tl[c * 64 + P * 4] = v;
    }
#pragma unroll
    for (int j = 0; j < 4; ++j) {        // flush: rows 4j+g, 256 B runs (plain)
      int rj = 4 * j + g;
      int P = c ^ (rj & 7);
      f32x4 w = *(f32x4*)&tl[rj * 64 + P * 4];
      *(f32x4*)&out[(row0 + rj) * VSZ + ct0 + c * 4] = w;
    }
  }
  {                                      // tail tile: cols 1984..1999, direct
    int ct = c0 + 1984;
    bf16x8 a0 = *(const bf16x8*)&Wbt[(ct + c) * KP + g * 8];
    bf16x8 a1 = *(const bf16x8*)&Wbt[(ct + c) * KP + 32 + g * 8];
    f32x4 acc = {0.f, 0.f, 0.f, 0.f};
    acc = __builtin_amdgcn_mfma_f32_16x16x32_bf16(a0, b0f, acc, 0, 0, 0);
    acc = __builtin_amdgcn_mfma_f32_16x16x32_bf16(a1, b1f, acc, 0, 0, 0);
    f32x4 v;
#pragma unroll
    for (int i = 0; i < 4; ++i) v[i] = acc[i] - L;
    *(f32x4*)&out[(row0 + c) * VSZ + ct + g * 4] = v;
  }
}

// ---------------------------------------------------------------------------
extern "C" void kernel_launch(void* const* d_in, const int* in_sizes, int n_in,
                              void* d_out, int out_size, void* d_ws, size_t ws_size,
                              hipStream_t stream) {
  (void)in_sizes; (void)n_in; (void)out_size; (void)ws_size;
  const int*   idx = (const int*)d_in[0];
  const float* emb = (const float*)d_in[1];
  const float* Wlr = (const float*)d_in[2];
  const float* blr = (const float*)d_in[3];
  const float* Wrl = (const float*)d_in[4];
  const float* brl = (const float*)d_in[5];
  const float* Who = (const float*)d_in[6];
  const float* bho = (const float*)d_in[7];
  const float* h0  = (const float*)d_in[8];
  float* out = (float*)d_out;

  char* ws = (char*)d_ws;
  float*          z    = (float*)(ws + 0);                 // 983040 B
  unsigned short* hcat = (unsigned short*)(ws + 983040);   // 524288 B
  unsigned short* Wbt  = (unsigned short*)(ws + 1507328);  // 4096000 B
  float*          part = (float*)(ws + 5603328);           // 262144 B

  k_prep<<<2024, 256, 0, stream>>>(idx, emb, Wlr, blr, Wrl, brl, z, Who, bho, Wbt);
  k_scan<<<64, 64, 0, stream>>>(z, Wlr, Wrl, h0, hcat);
  k_sumexp<<<dim3(32, 16), 256, 0, stream>>>(hcat, Wbt, part);
  k_writeout<<<dim3(64, 16), 256, 0, stream>>>(hcat, Wbt, part, out);
}

// Round 12
// 272.037 us; speedup vs baseline: 1.9074x; 1.2777x over previous
//
#include <hip/hip_runtime.h>

#define VSZ 32000
#define ESZ 150
#define HSZ 30
#define SSZ 128
#define BSZ 32
#define SB  4096   /* SSZ*BSZ */
#define KP  64     /* padded K: 60 dims + bias row + 3 zeros */

typedef __attribute__((ext_vector_type(8))) short bf16x8;
typedef __attribute__((ext_vector_type(4))) float f32x4;
typedef __attribute__((ext_vector_type(8))) unsigned short u16x8;

static __device__ __forceinline__ unsigned short f2bf(float f) {
  unsigned int u = __float_as_uint(f);
  u += 0x7fffu + ((u >> 16) & 1u);   // round-to-nearest-even
  return (unsigned short)(u >> 16);
}

static __device__ __forceinline__ float readlane_f(float v, int lane) {
  return __uint_as_float(__builtin_amdgcn_readlane(__float_as_uint(v), lane));
}

// ---------------------------------------------------------------------------
// K1: merged prep (proven in R11) — blocks 0..1023: input projection
// (4 tb per block, one per wave); blocks 1024..2023: Wbt transpose/pack.
// Independent halves; merging saves one launch boundary in the serial prefix.
// ---------------------------------------------------------------------------
__global__ __launch_bounds__(256) void k_prep(
    const int* __restrict__ idx, const float* __restrict__ emb,
    const float* __restrict__ Wlr, const float* __restrict__ blr,
    const float* __restrict__ Wrl, const float* __restrict__ brl,
    float* __restrict__ z,
    const float* __restrict__ Who, const float* __restrict__ bho,
    unsigned short* __restrict__ Wbt) {
  int bid = blockIdx.x;
  if (bid < 1024) {
    // ---- zproj: z[dir][t][b][j] = b_ih[j] + sum_e emb[idx[t,b]][e]*W[e][j]
    __shared__ float erow[4][ESZ];
    int wave = threadIdx.x >> 6, lane = threadIdx.x & 63;
    int tb = bid * 4 + wave;             // t*32 + b
    int row = idx[tb];
    for (int i = lane; i < ESZ; i += 64) erow[wave][i] = emb[row * ESZ + i];
    __syncthreads();
    int j = lane & 31, dir = lane >> 5;
    if (j < HSZ) {
      const float* W = dir ? Wrl : Wlr;
      float acc = dir ? brl[j] : blr[j];
#pragma unroll 10
      for (int e = 0; e < ESZ; ++e) acc = fmaf(erow[wave][e], W[e * HSZ + j], acc);
      z[(dir * SB + tb) * HSZ + j] = acc;   // z[dir][t][b][j]
    }
  } else {
    // ---- wprep: Wbt[v][k] (bf16, transposed W_ho; k=60 -> b_ho, 61..63 -> 0)
    int b2 = bid - 1024;                 // 0..999
    int v = (b2 % 125) * 256 + threadIdx.x;
    int kq = b2 / 125;
    u16x8 pack;
#pragma unroll
    for (int i = 0; i < 8; ++i) {
      int k = kq * 8 + i;
      float val = (k < 60) ? Who[k * VSZ + v] : ((k == 60) ? bho[v] : 0.f);
      pack[i] = f2bf(val);
    }
    *(u16x8*)&Wbt[v * KP + kq * 8] = pack;
  }
}

// ---------------------------------------------------------------------------
// K2: recurrent scans. 64 blocks x 64 threads; 1 chain (dir,b) per wave.
// ---------------------------------------------------------------------------
__global__ void k_scan(const float* __restrict__ z, const float* __restrict__ Wlr,
                       const float* __restrict__ Wrl, const float* __restrict__ h0,
                       unsigned short* __restrict__ hcat) {
  int j = threadIdx.x;                     // 0..63
  int chain = blockIdx.x;                  // 0..63
  int dir = chain >> 5, b = chain & 31;
  const float* W = dir ? Wrl : Wlr;
  float w2[HSZ];
#pragma unroll
  for (int k = 0; k < HSZ; ++k) w2[k] = (j < HSZ) ? W[(ESZ + k) * HSZ + j] : 0.f;
  float h = (j < HSZ) ? h0[j] : 0.f;
  bool wr = (j < 32);
  int dim = (j < HSZ) ? dir * HSZ + j : (dir ? 60 : 62) + (j - 30);
  unsigned short padbits = (dim == 60) ? f2bf(1.0f) : (unsigned short)0;
  const float* zc = z + dir * (SB * HSZ) + b * HSZ + j;
  int te0 = dir ? (SSZ - 1) : 0;
  float zv = (j < HSZ) ? zc[te0 * (BSZ * HSZ)] : 0.f;
  for (int t = 0; t < SSZ; ++t) {
    int te = dir ? (SSZ - 1 - t) : t;
    float zn = 0.f;
    if (t < SSZ - 1) {
      int ten = dir ? (SSZ - 2 - t) : (t + 1);
      zn = (j < HSZ) ? zc[ten * (BSZ * HSZ)] : 0.f;
    }
    int r = te * BSZ + b;
    if (wr) hcat[r * KP + dim] = (j < HSZ) ? f2bf(h) : padbits;  // pre-update state
    float a0 = zv, a1 = 0.f, a2 = 0.f, a3 = 0.f;
#pragma unroll
    for (int k = 0; k < 28; k += 4) {
      a0 = fmaf(readlane_f(h, k),     w2[k],     a0);
      a1 = fmaf(readlane_f(h, k + 1), w2[k + 1], a1);
      a2 = fmaf(readlane_f(h, k + 2), w2[k + 2], a2);
      a3 = fmaf(readlane_f(h, k + 3), w2[k + 3], a3);
    }
    a0 = fmaf(readlane_f(h, 28), w2[28], a0);
    a1 = fmaf(readlane_f(h, 29), w2[29], a1);
    float x = (a0 + a1) + (a2 + a3);
    float e = __expf(2.0f * x);
    h = 1.0f - __fdividef(2.0f, e + 1.0f);
    zv = zn;
  }
}

// ---------------------------------------------------------------------------
// K3: pass A — per-row sum of exp(logit). Swapped-operand MFMA. (R2 body)
// grid (32 Mblk, 16 Nblk) x 256. Block: 128 rows x 2000 cols; wave: 32 rows.
// ---------------------------------------------------------------------------
__global__ void k_sumexp(const unsigned short* __restrict__ hcat,
                         const unsigned short* __restrict__ Wbt,
                         float* __restrict__ part) {
  int mb = blockIdx.x, nb = blockIdx.y;
  int wave = threadIdx.x >> 6, lane = threadIdx.x & 63;
  int g = lane >> 4, c = lane & 15;
  int rbase = mb * 128 + wave * 32;
  bf16x8 bfr[2][2];                       // [row-group][k-split], held in regs
#pragma unroll
  for (int rg = 0; rg < 2; ++rg)
#pragma unroll
    for (int ks = 0; ks < 2; ++ks)
      bfr[rg][ks] = *(const bf16x8*)&hcat[(rbase + rg * 16 + c) * KP + ks * 32 + g * 8];
  float se[2] = {0.f, 0.f};
  int c0 = nb * 2000;
  for (int nt = 0; nt < 125; ++nt) {
    int ct = c0 + nt * 16;
    bf16x8 a0 = *(const bf16x8*)&Wbt[(ct + c) * KP + g * 8];
    bf16x8 a1 = *(const bf16x8*)&Wbt[(ct + c) * KP + 32 + g * 8];
#pragma unroll
    for (int rg = 0; rg < 2; ++rg) {
      f32x4 acc = {0.f, 0.f, 0.f, 0.f};
      acc = __builtin_amdgcn_mfma_f32_16x16x32_bf16(a0, bfr[rg][0], acc, 0, 0, 0);
      acc = __builtin_amdgcn_mfma_f32_16x16x32_bf16(a1, bfr[rg][1], acc, 0, 0, 0);
      se[rg] += (__expf(acc[0]) + __expf(acc[1])) + (__expf(acc[2]) + __expf(acc[3]));
    }
  }
#pragma unroll
  for (int rg = 0; rg < 2; ++rg) {
    se[rg] += __shfl_xor(se[rg], 16);
    se[rg] += __shfl_xor(se[rg], 32);
  }
  if (g == 0) {
#pragma unroll
    for (int rg = 0; rg < 2; ++rg)
      part[(rbase + rg * 16 + c) * 16 + nb] = se[rg];
  }
}

// ---------------------------------------------------------------------------
// K4: pass B — EXACT R5 writeout (best measured): per-wave 4 KB LDS slab,
// granule-XOR swizzle, NONTEMPORAL flush stores (NT bypasses per-XCD L2 so
// the 512 MB write stream doesn't evict Wbt/hcat — plain stores cost +70 us,
// R11). grid (64, 16) x 256.
// ---------------------------------------------------------------------------
__global__ __launch_bounds__(256) void k_writeout(
    const unsigned short* __restrict__ hcat,
    const unsigned short* __restrict__ Wbt,
    const float* __restrict__ part,
    float* __restrict__ out) {
  __shared__ float Lsh[64];
  __shared__ float slab[4][16 * 64];     // 4 waves x 4 KB
  int mb = blockIdx.x, nb = blockIdx.y;
  int tid = threadIdx.x;
  if (tid < 64) {
    const float* p = &part[(mb * 64 + tid) * 16];
    float s = 0.f;
#pragma unroll
    for (int k = 0; k < 16; ++k) s += p[k];
    Lsh[tid] = logf(s);
  }
  __syncthreads();
  int wave = tid >> 6, lane = tid & 63;
  int g = lane >> 4, c = lane & 15;
  int row0 = mb * 64 + wave * 16;
  bf16x8 b0f = *(const bf16x8*)&hcat[(row0 + c) * KP + g * 8];
  bf16x8 b1f = *(const bf16x8*)&hcat[(row0 + c) * KP + 32 + g * 8];
  float L = Lsh[wave * 16 + c];
  float* tl = slab[wave];
  int c0 = nb * 2000;
  for (int gq = 0; gq < 31; ++gq) {      // 31 groups of 4 tiles = cols 0..1983
    int ct0 = c0 + gq * 64;
#pragma unroll
    for (int t = 0; t < 4; ++t) {
      int ct = ct0 + t * 16;
      bf16x8 a0 = *(const bf16x8*)&Wbt[(ct + c) * KP + g * 8];
      bf16x8 a1 = *(const bf16x8*)&Wbt[(ct + c) * KP + 32 + g * 8];
      f32x4 acc = {0.f, 0.f, 0.f, 0.f};
      acc = __builtin_amdgcn_mfma_f32_16x16x32_bf16(a0, b0f, acc, 0, 0, 0);
      acc = __builtin_amdgcn_mfma_f32_16x16x32_bf16(a1, b1f, acc, 0, 0, 0);
      f32x4 v;
#pragma unroll
      for (int i = 0; i < 4; ++i) v[i] = acc[i] - L;
      int P = (t * 4 + g) ^ (c & 7);     // granule swizzle: row c, granule t*4+g
      *(f32x4*)&tl[c * 64 + P * 4] = v;
    }
#pragma unroll
    for (int j = 0; j < 4; ++j) {        // flush: rows 4j+g, 256 B runs (NT)
      int rj = 4 * j + g;
      int P = c ^ (rj & 7);
      f32x4 w = *(f32x4*)&tl[rj * 64 + P * 4];
      __builtin_nontemporal_store(w, (f32x4*)&out[(row0 + rj) * VSZ + ct0 + c * 4]);
    }
  }
  {                                      // tail tile: cols 1984..1999, direct
    int ct = c0 + 1984;
    bf16x8 a0 = *(const bf16x8*)&Wbt[(ct + c) * KP + g * 8];
    bf16x8 a1 = *(const bf16x8*)&Wbt[(ct + c) * KP + 32 + g * 8];
    f32x4 acc = {0.f, 0.f, 0.f, 0.f};
    acc = __builtin_amdgcn_mfma_f32_16x16x32_bf16(a0, b0f, acc, 0, 0, 0);
    acc = __builtin_amdgcn_mfma_f32_16x16x32_bf16(a1, b1f, acc, 0, 0, 0);
    f32x4 v;
#pragma unroll
    for (int i = 0; i < 4; ++i) v[i] = acc[i] - L;
    *(f32x4*)&out[(row0 + c) * VSZ + ct + g * 4] = v;
  }
}

// ---------------------------------------------------------------------------
extern "C" void kernel_launch(void* const* d_in, const int* in_sizes, int n_in,
                              void* d_out, int out_size, void* d_ws, size_t ws_size,
                              hipStream_t stream) {
  (void)in_sizes; (void)n_in; (void)out_size; (void)ws_size;
  const int*   idx = (const int*)d_in[0];
  const float* emb = (const float*)d_in[1];
  const float* Wlr = (const float*)d_in[2];
  const float* blr = (const float*)d_in[3];
  const float* Wrl = (const float*)d_in[4];
  const float* brl = (const float*)d_in[5];
  const float* Who = (const float*)d_in[6];
  const float* bho = (const float*)d_in[7];
  const float* h0  = (const float*)d_in[8];
  float* out = (float*)d_out;

  char* ws = (char*)d_ws;
  float*          z    = (float*)(ws + 0);                 // 983040 B
  unsigned short* hcat = (unsigned short*)(ws + 983040);   // 524288 B
  unsigned short* Wbt  = (unsigned short*)(ws + 1507328);  // 4096000 B
  float*          part = (float*)(ws + 5603328);           // 262144 B

  k_prep<<<2024, 256, 0, stream>>>(idx, emb, Wlr, blr, Wrl, brl, z, Who, bho, Wbt);
  k_scan<<<64, 64, 0, stream>>>(z, Wlr, Wrl, h0, hcat);
  k_sumexp<<<dim3(32, 16), 256, 0, stream>>>(hcat, Wbt, part);
  k_writeout<<<dim3(64, 16), 256, 0, stream>>>(hcat, Wbt, part, out);
}